// Round 8
// baseline (1084.499 us; speedup 1.0000x reference)
//
#include <hip/hip_runtime.h>

#define D 64
#define HOUR_PERIOD 6
#define NBLK 1024
#define NTHR 256

// ---------- dtype helpers ----------
__device__ __forceinline__ float bf2f(unsigned short u) {
    union { unsigned int i; float f; } v; v.i = ((unsigned int)u) << 16; return v.f;
}
__device__ __forceinline__ unsigned short f2bf(float f) {
    union { float fl; unsigned int i; } v; v.fl = f;
    unsigned int x = v.i;
    return (unsigned short)((x + 0x7fffu + ((x >> 16) & 1u)) >> 16);
}
__device__ __forceinline__ float4 ld4(const void* base, int idx4, int fp32) {
    if (fp32) return reinterpret_cast<const float4*>(base)[idx4];
    ushort4 u = reinterpret_cast<const ushort4*>(base)[idx4];
    return make_float4(bf2f(u.x), bf2f(u.y), bf2f(u.z), bf2f(u.w));
}
__device__ __forceinline__ float ld1(const void* base, int i, int fp32) {
    return fp32 ? reinterpret_cast<const float*>(base)[i]
                : bf2f(reinterpret_cast<const unsigned short*>(base)[i]);
}

// ---------- agent-scope (device-coherent) accessors for cross-phase data ----------
__device__ __forceinline__ int aload(const int* p) {
    return __hip_atomic_load(p, __ATOMIC_RELAXED, __HIP_MEMORY_SCOPE_AGENT);
}
__device__ __forceinline__ unsigned aloadu(const unsigned* p) {
    return __hip_atomic_load(p, __ATOMIC_RELAXED, __HIP_MEMORY_SCOPE_AGENT);
}
__device__ __forceinline__ float aloadf(const float* p) {
    return __hip_atomic_load(p, __ATOMIC_RELAXED, __HIP_MEMORY_SCOPE_AGENT);
}
__device__ __forceinline__ void astore(int* p, int v) {
    __hip_atomic_store(p, v, __ATOMIC_RELAXED, __HIP_MEMORY_SCOPE_AGENT);
}
__device__ __forceinline__ void astoreu(unsigned* p, unsigned v) {
    __hip_atomic_store(p, v, __ATOMIC_RELAXED, __HIP_MEMORY_SCOPE_AGENT);
}
__device__ __forceinline__ void astoref(float* p, float v) {
    __hip_atomic_store(p, v, __ATOMIC_RELAXED, __HIP_MEMORY_SCOPE_AGENT);
}

// ---------- DPP 16-lane row reduction (VALU pipe, no DS traffic) ----------
template <int CTRL>
__device__ __forceinline__ float dpp_add(float v) {
    union { float f; int i; } a, b;
    a.f = v;
    b.i = __builtin_amdgcn_update_dpp(0, a.i, CTRL, 0xF, 0xF, true);
    return v + b.f;
}
__device__ __forceinline__ float qsum(float v) {
    v = dpp_add<0x128>(v);   // row_ror:8
    v = dpp_add<0x124>(v);   // row_ror:4
    v = dpp_add<0x122>(v);   // row_ror:2
    v = dpp_add<0x121>(v);   // row_ror:1
    return v;
}
__device__ __forceinline__ float wsum64(float v) {
    #pragma unroll
    for (int off = 32; off; off >>= 1) v += __shfl_xor(v, off, 64);
    return v;
}
__device__ __forceinline__ int wredi(int v) {
    #pragma unroll
    for (int off = 32; off; off >>= 1) v += __shfl_xor(v, off, 64);
    return v;
}

// ---------- device-wide barrier (all NBLK blocks co-resident by launch_bounds) ----
__device__ __forceinline__ void gbar(int* bar, int idx) {
    __threadfence();                       // release: flush this wave's writes
    __syncthreads();                       // all threads of block flushed
    if (threadIdx.x == 0) {
        __hip_atomic_fetch_add(&bar[idx], 1, __ATOMIC_RELEASE, __HIP_MEMORY_SCOPE_AGENT);
        while (__hip_atomic_load(&bar[idx], __ATOMIC_ACQUIRE, __HIP_MEMORY_SCOPE_AGENT) < NBLK)
            __builtin_amdgcn_s_sleep(8);
    }
    __syncthreads();
    __threadfence();                       // acquire: invalidate stale cache lines
}

// ================= mega-kernel: all phases in one dispatch =================
// ws: bar(16) cnt(M) row(M) parts(256) trel(384) recs(ET); bar+cnt pre-zeroed by memset.
__global__ __launch_bounds__(NTHR, 4) void k_mega(
    const void* __restrict__ nfeat, const void* __restrict__ cemb,
    const void* __restrict__ rel_emb, const void* __restrict__ norm_emb,
    const void* __restrict__ hour_emb, const void* __restrict__ trw,
    const void* __restrict__ trb,
    const int* __restrict__ src, const int* __restrict__ dst,
    const int* __restrict__ ftype, const int* __restrict__ hourid,
    const int* __restrict__ csrc, const int* __restrict__ cdst,
    int* bar, int* cnt, int* row, int* parts, float* trel, unsigned* recs,
    void* __restrict__ out, int N, int NC, int E, int EC)
{
    const int M = N + NC, b = blockIdx.x, t = threadIdx.x;
    const int tg = b * NTHR + t;
    const int TG = NBLK * NTHR;
    const int nparts = (M + 1023) >> 10;   // <= 256

    __shared__ float smem[14 * D + HOUR_PERIOD * D];   // P0: smem[0..63]=mix; P4: tables
    __shared__ int smi[8];
    __shared__ int sflag;

    // ---- block-local dtype detect (rel_emb rows L2-normalized -> |v|<=1 if bf16) ----
    if (t < 64) {
        float da = bf2f(reinterpret_cast<const unsigned short*>(rel_emb)[t]);
        float db = bf2f(reinterpret_cast<const unsigned short*>(rel_emb)[t + 64]);
        int bad = (!(fabsf(da) <= 100.f)) || (!(fabsf(db) <= 100.f));
        unsigned long long m = __ballot(bad);
        if (t == 0) sflag = (m != 0ull) ? 1 : 0;   // 1 => fp32 inputs/outputs
    }
    __syncthreads();
    const int f = sflag;

    // ================= P0: trel table (blocks 0..5) =================
    if (b < HOUR_PERIOD) {
        if (t < 64) {
            int last = (b - 1 + HOUR_PERIOD) % HOUR_PERIOD;
            int next = (b + 1) % HOUR_PERIOD;
            smem[t] = (ld1(hour_emb, last * D + t, f) + ld1(hour_emb, b * D + t, f) +
                       ld1(hour_emb, next * D + t, f)) * (1.f / 3.f);
        }
        __syncthreads();
        if (t < 64) {
            float y = ld1(trb, t, f);
            #pragma unroll
            for (int k = 0; k < D; ++k) y += smem[k] * ld1(trw, t * D + k, f);
            float ss = wsum64(y * y);
            astoref(&trel[b * D + t], y / fmaxf(sqrtf(ss), 1e-12f));
        }
        __syncthreads();
    }

    // ================= P1: unified histogram (cnt pre-zeroed by memset) ==========
    const int mainT = (E + 3) >> 2, catT = (EC + 3) >> 2;
    for (int i = tg; i < mainT + catT; i += TG) {
        if (i < mainT) {
            int e4 = i * 4;
            if (e4 + 3 < E) {
                int4 dv = reinterpret_cast<const int4*>(dst)[i];
                atomicAdd(&cnt[dv.x], 1); atomicAdd(&cnt[dv.y], 1);
                atomicAdd(&cnt[dv.z], 1); atomicAdd(&cnt[dv.w], 1);
            } else {
                for (int k = e4; k < E; ++k) atomicAdd(&cnt[dst[k]], 1);
            }
        } else {
            int j = i - mainT, e4 = (i - mainT) * 4;
            if (e4 + 3 < EC) {
                int4 dv = reinterpret_cast<const int4*>(cdst)[j];
                atomicAdd(&cnt[N + dv.x], 1); atomicAdd(&cnt[N + dv.y], 1);
                atomicAdd(&cnt[N + dv.z], 1); atomicAdd(&cnt[N + dv.w], 1);
            } else {
                for (int k = e4; k < EC; ++k) atomicAdd(&cnt[N + cdst[k]], 1);
            }
        }
    }
    gbar(bar, 0);

    // ---- preload P4 tables (inputs are immutable; trel via agent loads) ----
    {
        float* srel  = smem;
        float* snorm = smem + 7 * D;
        float* strel = smem + 14 * D;
        for (int i = t; i < 7 * D; i += NTHR) srel[i] = ld1(rel_emb, i, f);
        for (int i = t; i < 7 * D; i += NTHR) snorm[i] = ld1(norm_emb, i, f);
        for (int i = t; i < HOUR_PERIOD * D; i += NTHR) strel[i] = aloadf(&trel[i]);
    }

    // ================= P2a: per-chunk (1024 elems) totals =================
    if (b < nparts) {
        int idx = b * 256 + t;
        int i0 = idx * 4, s = 0;
        if (i0 + 3 < M) {
            int4 c = reinterpret_cast<const int4*>(cnt)[idx];
            s = c.x + c.y + c.z + c.w;
        } else {
            for (int k = i0; k < M; ++k) s += cnt[k];
        }
        s = wredi(s);
        int lane = t & 63, wv = t >> 6;
        if (lane == 0) smi[wv] = s;
        __syncthreads();
        if (t == 0) astore(&parts[b], smi[0] + smi[1] + smi[2] + smi[3]);
    }
    gbar(bar, 1);

    // ================= P2b: exclusive scan -> row (bump cursor) =================
    if (b < nparts) {
        int lane = t & 63, wv = t >> 6;
        int pv = (t < b) ? aload(&parts[t]) : 0;
        pv = wredi(pv);
        if (lane == 0) smi[wv] = pv;
        int idx = b * 256 + t;
        int i0 = idx * 4;
        int c0 = 0, c1 = 0, c2 = 0, c3 = 0;
        if (i0 + 3 < M) {
            int4 c = reinterpret_cast<const int4*>(cnt)[idx];
            c0 = c.x; c1 = c.y; c2 = c.z; c3 = c.w;
        } else {
            if (i0 + 0 < M) c0 = cnt[i0 + 0];
            if (i0 + 1 < M) c1 = cnt[i0 + 1];
            if (i0 + 2 < M) c2 = cnt[i0 + 2];
            if (i0 + 3 < M) c3 = cnt[i0 + 3];
        }
        int s = c0 + c1 + c2 + c3;
        int x = s;
        #pragma unroll
        for (int off = 1; off < 64; off <<= 1) {
            int y = __shfl_up(x, off, 64);
            if (lane >= off) x += y;
        }
        if (lane == 63) smi[4 + wv] = x;
        __syncthreads();
        int base = smi[0] + smi[1] + smi[2] + smi[3];
        int wbase = 0;
        #pragma unroll
        for (int w = 0; w < 4; ++w) wbase += (w < wv) ? smi[4 + w] : 0;
        int run = base + wbase + (x - s);
        if (i0 + 0 < M) { astore(&row[i0 + 0], run); run += c0; }
        if (i0 + 1 < M) { astore(&row[i0 + 1], run); run += c1; }
        if (i0 + 2 < M) { astore(&row[i0 + 2], run); run += c2; }
        if (i0 + 3 < M) { astore(&row[i0 + 3], run); run += c3; }
    }
    gbar(bar, 2);

    // ================= P3: scatter packed edge records (bump row) =================
    // main: src(17b) | ftype(3b)<<17 | hour(3b)<<20 ; cat: csrc plain
    for (int i = tg; i < mainT + catT; i += TG) {
        if (i < mainT) {
            int e4 = i * 4;
            if (e4 + 3 < E) {
                int4 s4 = reinterpret_cast<const int4*>(src)[i];
                int4 d4 = reinterpret_cast<const int4*>(dst)[i];
                int4 f4 = reinterpret_cast<const int4*>(ftype)[i];
                int4 h4 = reinterpret_cast<const int4*>(hourid)[i];
                int p;
                p = atomicAdd(&row[d4.x], 1);
                astoreu(&recs[p], (unsigned)s4.x | ((unsigned)f4.x << 17) | ((unsigned)h4.x << 20));
                p = atomicAdd(&row[d4.y], 1);
                astoreu(&recs[p], (unsigned)s4.y | ((unsigned)f4.y << 17) | ((unsigned)h4.y << 20));
                p = atomicAdd(&row[d4.z], 1);
                astoreu(&recs[p], (unsigned)s4.z | ((unsigned)f4.z << 17) | ((unsigned)h4.z << 20));
                p = atomicAdd(&row[d4.w], 1);
                astoreu(&recs[p], (unsigned)s4.w | ((unsigned)f4.w << 17) | ((unsigned)h4.w << 20));
            } else {
                for (int k = e4; k < E; ++k) {
                    int p = atomicAdd(&row[dst[k]], 1);
                    astoreu(&recs[p], (unsigned)src[k] | ((unsigned)ftype[k] << 17) |
                                      ((unsigned)hourid[k] << 20));
                }
            }
        } else {
            int j = i - mainT, e4 = (i - mainT) * 4;
            if (e4 + 3 < EC) {
                int4 s4 = reinterpret_cast<const int4*>(csrc)[j];
                int4 d4 = reinterpret_cast<const int4*>(cdst)[j];
                int p;
                p = atomicAdd(&row[N + d4.x], 1); astoreu(&recs[p], (unsigned)s4.x);
                p = atomicAdd(&row[N + d4.y], 1); astoreu(&recs[p], (unsigned)s4.y);
                p = atomicAdd(&row[N + d4.z], 1); astoreu(&recs[p], (unsigned)s4.z);
                p = atomicAdd(&row[N + d4.w], 1); astoreu(&recs[p], (unsigned)s4.w);
            } else {
                for (int k = e4; k < EC; ++k) {
                    int p = atomicAdd(&row[N + cdst[k]], 1);
                    astoreu(&recs[p], (unsigned)csrc[k]);
                }
            }
        }
    }
    gbar(bar, 3);

    // ================= P4: fused aggregation for BOTH graphs =================
    // row[d] = segment END after bumping; start = end - cnt[d].
    // out[d] = sum_e es_e * h_e / sum_e es_e  (softmax denominator factors out).
    {
        float* srel  = smem;
        float* snorm = smem + 7 * D;
        float* strel = smem + 14 * D;
        int l = t & 15, qw = t >> 4;
        int ngrp = (M + 15) >> 4;
        for (int grp = b; grp < ngrp; grp += NBLK) {
            int d = grp * 16 + qw;
            if (d >= M) continue;
            int i1 = aload(&row[d]);
            int i0 = i1 - aload(&cnt[d]);
            float a0 = 0.f, a1 = 0.f, a2 = 0.f, a3 = 0.f, se = 0.f;
            if (d < N) {
                // ---- main graph (TransH on relation + time hyperplanes) ----
                float4 tt = ld4(nfeat, d * 16 + l, f);
                float4 qv = *reinterpret_cast<float4*>(&snorm[5 * D + l * 4]);
                unsigned pkA = 0, pkB = 0;
                float4 hA = make_float4(0,0,0,0), hB = hA;
                if (i0 < i1)     { pkA = aloadu(&recs[i0]);     hA = ld4(nfeat, (int)(pkA & 0x1FFFF) * 16 + l, f); }
                if (i0 + 1 < i1) { pkB = aloadu(&recs[i0 + 1]); hB = ld4(nfeat, (int)(pkB & 0x1FFFF) * 16 + l, f); }
                for (int i = i0; i < i1; ++i) {
                    unsigned cpk = pkA; float4 ch = hA;
                    pkA = pkB; hA = hB;
                    if (i + 2 < i1) { pkB = aloadu(&recs[i + 2]); hB = ld4(nfeat, (int)(pkB & 0x1FFFF) * 16 + l, f); }
                    int ft = (cpk >> 17) & 7, hh = (cpk >> 20) & 7;
                    float4 nn4 = *reinterpret_cast<float4*>(&snorm[ft * D + l * 4]);
                    float4 rr4 = *reinterpret_cast<float4*>(&srel[ft * D + l * 4]);
                    float4 tr4 = *reinterpret_cast<float4*>(&strel[hh * D + l * 4]);
                    float w0 = ch.x - tt.x, w1 = ch.y - tt.y, w2 = ch.z - tt.z, w3 = ch.w - tt.w;
                    float al = qsum(w0*nn4.x + w1*nn4.y + w2*nn4.z + w3*nn4.w);
                    float be = qsum(w0*qv.x + w1*qv.y + w2*qv.z + w3*qv.w);
                    float u0 = w0 + rr4.x - al*nn4.x, u1 = w1 + rr4.y - al*nn4.y,
                          u2 = w2 + rr4.z - al*nn4.z, u3 = w3 + rr4.w - al*nn4.w;
                    float v0 = w0 + tr4.x - be*qv.x, v1 = w1 + tr4.y - be*qv.y,
                          v2 = w2 + tr4.z - be*qv.z, v3 = w3 + tr4.w - be*qv.w;
                    float ssq = qsum(u0*u0 + u1*u1 + u2*u2 + u3*u3 +
                                     v0*v0 + v1*v1 + v2*v2 + v3*v3);
                    float es = __expf(__expf(-ssq));   // exp(score*score_t), arg in (0,1]
                    a0 += es * ch.x; a1 += es * ch.y; a2 += es * ch.z; a3 += es * ch.w;
                    se += es;
                }
            } else {
                // ---- category graph (TransE) ----
                float4 tt = ld4(cemb, (d - N) * 16 + l, f);
                float4 r6 = *reinterpret_cast<float4*>(&srel[6 * D + l * 4]);
                float b0 = r6.x - tt.x, b1 = r6.y - tt.y, b2 = r6.z - tt.z, b3 = r6.w - tt.w;
                unsigned pkA = 0, pkB = 0;
                float4 hA = make_float4(0,0,0,0), hB = hA;
                if (i0 < i1)     { pkA = aloadu(&recs[i0]);     hA = ld4(cemb, (int)pkA * 16 + l, f); }
                if (i0 + 1 < i1) { pkB = aloadu(&recs[i0 + 1]); hB = ld4(cemb, (int)pkB * 16 + l, f); }
                for (int i = i0; i < i1; ++i) {
                    float4 ch = hA;
                    pkA = pkB; hA = hB;
                    if (i + 2 < i1) { pkB = aloadu(&recs[i + 2]); hB = ld4(cemb, (int)pkB * 16 + l, f); }
                    float d0 = ch.x + b0, d1 = ch.y + b1, d2 = ch.z + b2, d3 = ch.w + b3;
                    float ssq = qsum(d0*d0 + d1*d1 + d2*d2 + d3*d3);
                    float es = __expf(__expf(-ssq));
                    a0 += es * ch.x; a1 += es * ch.y; a2 += es * ch.z; a3 += es * ch.w;
                    se += es;
                }
            }
            float inv = (se > 0.f) ? 1.f / se : 0.f;   // zero-degree row -> zeros
            int oi = d * 16 + l;
            if (f) {
                reinterpret_cast<float4*>(out)[oi] = make_float4(a0*inv, a1*inv, a2*inv, a3*inv);
            } else {
                ushort4 o;
                o.x = f2bf(a0*inv); o.y = f2bf(a1*inv); o.z = f2bf(a2*inv); o.w = f2bf(a3*inv);
                reinterpret_cast<ushort4*>(out)[oi] = o;
            }
        }
    }
}

extern "C" void kernel_launch(void* const* d_in, const int* in_sizes, int n_in,
                              void* d_out, int out_size, void* d_ws, size_t ws_size,
                              hipStream_t stream) {
    const void* nfeat    = d_in[0];
    const void* cemb     = d_in[1];
    const void* rel_emb  = d_in[2];
    const void* norm_emb = d_in[3];
    const void* hour_emb = d_in[4];
    const void* trw      = d_in[5];
    const void* trb      = d_in[6];
    const int* src    = (const int*)d_in[7];
    const int* dst    = (const int*)d_in[8];
    const int* ftype  = (const int*)d_in[9];
    const int* hourid = (const int*)d_in[10];
    const int* csrc   = (const int*)d_in[11];
    const int* cdst   = (const int*)d_in[12];

    int N  = in_sizes[0] / D;
    int NC = in_sizes[1] / D;
    int E  = in_sizes[7];
    int EC = in_sizes[11];
    int M  = N + NC;

    // ---- ws layout (4B units): bar(16) cnt(M) | row(M) parts(256) trel(384) recs(ET) ----
    int* ws     = (int*)d_ws;
    int* bar    = ws;
    int* cnt    = ws + 16;
    int* row    = cnt + M;
    int* parts  = row + M;
    float* trel = (float*)(parts + 256);
    unsigned* recs = (unsigned*)(trel + HOUR_PERIOD * D);

    // zero bar + cnt (contiguous); capture-safe async memset
    hipMemsetAsync(ws, 0, (size_t)(16 + M) * 4, stream);

    k_mega<<<NBLK, NTHR, 0, stream>>>(nfeat, cemb, rel_emb, norm_emb,
                                      hour_emb, trw, trb,
                                      src, dst, ftype, hourid, csrc, cdst,
                                      bar, cnt, row, parts, trel, recs,
                                      d_out, N, NC, E, EC);
}

// Round 9
// 257.309 us; speedup vs baseline: 4.2148x; 4.2148x over previous
//
#include <hip/hip_runtime.h>

#define D 64
#define HOUR_PERIOD 6

// ---------- dtype helpers ----------
__device__ __forceinline__ float bf2f(unsigned short u) {
    union { unsigned int i; float f; } v; v.i = ((unsigned int)u) << 16; return v.f;
}
__device__ __forceinline__ unsigned short f2bf(float f) {
    union { float fl; unsigned int i; } v; v.fl = f;
    unsigned int x = v.i;
    return (unsigned short)((x + 0x7fffu + ((x >> 16) & 1u)) >> 16);
}
__device__ __forceinline__ float4 ld4(const void* base, int idx4, int fp32) {
    if (fp32) return reinterpret_cast<const float4*>(base)[idx4];
    ushort4 u = reinterpret_cast<const ushort4*>(base)[idx4];
    return make_float4(bf2f(u.x), bf2f(u.y), bf2f(u.z), bf2f(u.w));
}
__device__ __forceinline__ float ld1(const void* base, int i, int fp32) {
    return fp32 ? reinterpret_cast<const float*>(base)[i]
                : bf2f(reinterpret_cast<const unsigned short*>(base)[i]);
}
// per-wave dtype detect: rel_emb rows are L2-normalized -> |v|<=1 if truly bf16
__device__ __forceinline__ int detect_f(const void* rel_emb) {
    int lane = threadIdx.x & 63;
    float da = bf2f(reinterpret_cast<const unsigned short*>(rel_emb)[lane]);
    float db = bf2f(reinterpret_cast<const unsigned short*>(rel_emb)[lane + 64]);
    int bad = (!(fabsf(da) <= 100.f)) || (!(fabsf(db) <= 100.f));
    unsigned long long m = __ballot(bad);
    return (m != 0ull) ? 1 : 0;   // 1 => fp32 inputs/outputs
}

// ---------- DPP 16-lane row reduction (VALU pipe, no DS traffic) ----------
template <int CTRL>
__device__ __forceinline__ float dpp_add(float v) {
    union { float f; int i; } a, b;
    a.f = v;
    b.i = __builtin_amdgcn_update_dpp(0, a.i, CTRL, 0xF, 0xF, true);
    return v + b.f;
}
__device__ __forceinline__ float qsum(float v) {
    v = dpp_add<0x128>(v);   // row_ror:8
    v = dpp_add<0x124>(v);   // row_ror:4
    v = dpp_add<0x122>(v);   // row_ror:2
    v = dpp_add<0x121>(v);   // row_ror:1
    return v;
}
__device__ __forceinline__ float wsum64(float v) {
    #pragma unroll
    for (int off = 32; off; off >>= 1) v += __shfl_xor(v, off, 64);
    return v;
}
__device__ __forceinline__ int wredi(int v) {
    #pragma unroll
    for (int off = 32; off; off >>= 1) v += __shfl_xor(v, off, 64);
    return v;
}

// ---------- hist (+ trel table in blocks 0..5); cnt pre-zeroed by memset ----------
__global__ void k_hist(const int* __restrict__ dst, const int* __restrict__ cdst,
                       int* __restrict__ cnt,
                       const void* __restrict__ hour_emb, const void* __restrict__ trw,
                       const void* __restrict__ trb, const void* __restrict__ rel_emb,
                       float* __restrict__ trel, int E, int EC, int N) {
    int b = blockIdx.x, t = threadIdx.x;
    if (b < HOUR_PERIOD) {
        __shared__ float mix[D];
        int f = 0;
        if (t < 64) {
            f = detect_f(rel_emb);
            int last = (b - 1 + HOUR_PERIOD) % HOUR_PERIOD;
            int next = (b + 1) % HOUR_PERIOD;
            mix[t] = (ld1(hour_emb, last * D + t, f) + ld1(hour_emb, b * D + t, f) +
                      ld1(hour_emb, next * D + t, f)) * (1.f / 3.f);
        }
        __syncthreads();
        if (t < 64) {
            float y = ld1(trb, t, f);
            #pragma unroll
            for (int k = 0; k < D; ++k) y += mix[k] * ld1(trw, t * D + k, f);
            float ss = wsum64(y * y);
            trel[b * D + t] = y / fmaxf(sqrtf(ss), 1e-12f);
        }
    }
    int tid = b * 256 + t;
    int mainT = (E + 3) >> 2;
    if (tid < mainT) {
        int e4 = tid * 4;
        if (e4 + 3 < E) {
            int4 dv = reinterpret_cast<const int4*>(dst)[tid];
            atomicAdd(&cnt[dv.x], 1); atomicAdd(&cnt[dv.y], 1);
            atomicAdd(&cnt[dv.z], 1); atomicAdd(&cnt[dv.w], 1);
        } else {
            for (int k = e4; k < E; ++k) atomicAdd(&cnt[dst[k]], 1);
        }
    } else {
        int j = tid - mainT, e4 = j * 4;
        if (e4 + 3 < EC) {
            int4 dv = reinterpret_cast<const int4*>(cdst)[j];
            atomicAdd(&cnt[N + dv.x], 1); atomicAdd(&cnt[N + dv.y], 1);
            atomicAdd(&cnt[N + dv.z], 1); atomicAdd(&cnt[N + dv.w], 1);
        } else {
            for (int k = e4; k < EC; ++k) atomicAdd(&cnt[N + cdst[k]], 1);
        }
    }
}

// ---------- single-dispatch scan with decoupled lookback ----------
// Each block: local total -> publish parts[b]=total+1 (release) -> all publish
// BEFORE any spin, so no deadlock regardless of scheduling. parts pre-zeroed.
__global__ void k_scan(const int* __restrict__ cnt, int* __restrict__ parts,
                       int* __restrict__ row, int n) {
    __shared__ int smw[4], smb[4];
    int b = blockIdx.x, t = threadIdx.x;
    int lane = t & 63, wv = t >> 6;
    int idx = b * 256 + t, i0 = idx * 4;
    int c0 = 0, c1 = 0, c2 = 0, c3 = 0;
    if (i0 + 3 < n) {
        int4 c = reinterpret_cast<const int4*>(cnt)[idx];
        c0 = c.x; c1 = c.y; c2 = c.z; c3 = c.w;
    } else {
        if (i0 + 0 < n) c0 = cnt[i0 + 0];
        if (i0 + 1 < n) c1 = cnt[i0 + 1];
        if (i0 + 2 < n) c2 = cnt[i0 + 2];
        if (i0 + 3 < n) c3 = cnt[i0 + 3];
    }
    int s = c0 + c1 + c2 + c3;
    int x = s;   // inclusive wave scan
    #pragma unroll
    for (int off = 1; off < 64; off <<= 1) {
        int y = __shfl_up(x, off, 64);
        if (lane >= off) x += y;
    }
    if (lane == 63) smw[wv] = x;
    __syncthreads();
    if (t == 0) {
        int total = smw[0] + smw[1] + smw[2] + smw[3];
        __hip_atomic_store(&parts[b], total + 1, __ATOMIC_RELEASE, __HIP_MEMORY_SCOPE_AGENT);
    }
    // lookback: thread t spins on parts[t] for t < b  (nparts <= 256 guaranteed)
    int pv = 0;
    if (t < b) {
        int v;
        while ((v = __hip_atomic_load(&parts[t], __ATOMIC_ACQUIRE,
                                      __HIP_MEMORY_SCOPE_AGENT)) == 0)
            __builtin_amdgcn_s_sleep(2);
        pv = v - 1;
    }
    pv = wredi(pv);
    if (lane == 0) smb[wv] = pv;
    __syncthreads();
    int base = smb[0] + smb[1] + smb[2] + smb[3];
    int wbase = 0;
    #pragma unroll
    for (int w = 0; w < 4; ++w) wbase += (w < wv) ? smw[w] : 0;
    int run = base + wbase + (x - s);   // exclusive prefix
    if (i0 + 0 < n) { row[i0 + 0] = run; run += c0; }
    if (i0 + 1 < n) { row[i0 + 1] = run; run += c1; }
    if (i0 + 2 < n) { row[i0 + 2] = run; run += c2; }
    if (i0 + 3 < n) { row[i0 + 3] = run; run += c3; }
}

// ---------- unified scatter (4 edges/thread); bumps row[d] in place ----------
// main: src(17b) | ftype(3b)<<17 | hour(3b)<<20 ; cat: csrc plain
__global__ void k_scatter(const int* __restrict__ src, const int* __restrict__ dst,
                          const int* __restrict__ ft, const int* __restrict__ hh,
                          const int* __restrict__ csrc, const int* __restrict__ cdst,
                          int* __restrict__ row, unsigned* __restrict__ recs,
                          int E, int EC, int N) {
    int tid = blockIdx.x * blockDim.x + threadIdx.x;
    int mainT = (E + 3) / 4;
    if (tid < mainT) {
        int i = tid * 4;
        if (i + 3 < E) {
            int4 s4 = reinterpret_cast<const int4*>(src)[tid];
            int4 d4 = reinterpret_cast<const int4*>(dst)[tid];
            int4 f4 = reinterpret_cast<const int4*>(ft)[tid];
            int4 h4 = reinterpret_cast<const int4*>(hh)[tid];
            int p;
            p = atomicAdd(&row[d4.x], 1);
            recs[p] = (unsigned)s4.x | ((unsigned)f4.x << 17) | ((unsigned)h4.x << 20);
            p = atomicAdd(&row[d4.y], 1);
            recs[p] = (unsigned)s4.y | ((unsigned)f4.y << 17) | ((unsigned)h4.y << 20);
            p = atomicAdd(&row[d4.z], 1);
            recs[p] = (unsigned)s4.z | ((unsigned)f4.z << 17) | ((unsigned)h4.z << 20);
            p = atomicAdd(&row[d4.w], 1);
            recs[p] = (unsigned)s4.w | ((unsigned)f4.w << 17) | ((unsigned)h4.w << 20);
        } else {
            for (int k = i; k < E; ++k) {
                int p = atomicAdd(&row[dst[k]], 1);
                recs[p] = (unsigned)src[k] | ((unsigned)ft[k] << 17) | ((unsigned)hh[k] << 20);
            }
        }
    } else {
        int j = (tid - mainT) * 4;
        if (j + 3 < EC) {
            int4 s4 = reinterpret_cast<const int4*>(csrc)[tid - mainT];
            int4 d4 = reinterpret_cast<const int4*>(cdst)[tid - mainT];
            int p;
            p = atomicAdd(&row[N + d4.x], 1); recs[p] = (unsigned)s4.x;
            p = atomicAdd(&row[N + d4.y], 1); recs[p] = (unsigned)s4.y;
            p = atomicAdd(&row[N + d4.z], 1); recs[p] = (unsigned)s4.z;
            p = atomicAdd(&row[N + d4.w], 1); recs[p] = (unsigned)s4.w;
        } else {
            for (int k = j; k < EC; ++k) {
                int p = atomicAdd(&row[N + cdst[k]], 1);
                recs[p] = (unsigned)csrc[k];
            }
        }
    }
}

// ---------- fused aggregation: ONE WAVE PER NODE, 4 edges across quarter-waves ----
// row[d] = segment END after bumping; start = end - cnt[d].
// out[d] = sum_e es_e * h_e / sum_e es_e  (softmax denominator factors out).
__launch_bounds__(256, 4)
__global__ void k_fused(const void* __restrict__ nfeat, const void* __restrict__ cemb,
                        const void* __restrict__ rel_emb, const void* __restrict__ norm_emb,
                        const float* __restrict__ trel,
                        const int* __restrict__ row, const int* __restrict__ cnt,
                        const unsigned* __restrict__ recs,
                        void* __restrict__ out, int N, int M) {
    int t = threadIdx.x;
    int f = detect_f(rel_emb);
    __shared__ float srel[7 * D], snorm[7 * D], strel[HOUR_PERIOD * D];
    for (int i = t; i < 7 * D; i += 256) srel[i] = ld1(rel_emb, i, f);
    for (int i = t; i < 7 * D; i += 256) snorm[i] = ld1(norm_emb, i, f);
    for (int i = t; i < HOUR_PERIOD * D; i += 256) strel[i] = trel[i];
    __syncthreads();
    int lane = t & 63, w = t >> 6;
    int l = lane & 15, q = lane >> 4;     // dim quarter / edge slot
    int dbase = (blockIdx.x * 4 + w) * 4; // 4 consecutive nodes per wave
    for (int d = dbase; d < dbase + 4 && d < M; ++d) {
        int i1 = row[d];
        int i0 = i1 - cnt[d];
        float a0 = 0.f, a1 = 0.f, a2 = 0.f, a3 = 0.f, se = 0.f;
        if (d < N) {
            // ---- main graph (TransH on relation + time hyperplanes) ----
            float4 tt = ld4(nfeat, d * 16 + l, f);
            float4 qv = *reinterpret_cast<float4*>(&snorm[5 * D + l * 4]);
            int i = i0 + q;
            unsigned pkA = 0; float4 hA = make_float4(0, 0, 0, 0);
            if (i < i1) { pkA = recs[i]; hA = ld4(nfeat, (int)(pkA & 0x1FFFF) * 16 + l, f); }
            for (; i < i1; i += 4) {
                unsigned cpk = pkA; float4 ch = hA;
                if (i + 4 < i1) { pkA = recs[i + 4]; hA = ld4(nfeat, (int)(pkA & 0x1FFFF) * 16 + l, f); }
                int ft = (cpk >> 17) & 7, hh = (cpk >> 20) & 7;
                float4 nn4 = *reinterpret_cast<float4*>(&snorm[ft * D + l * 4]);
                float4 rr4 = *reinterpret_cast<float4*>(&srel[ft * D + l * 4]);
                float4 tr4 = *reinterpret_cast<float4*>(&strel[hh * D + l * 4]);
                float w0 = ch.x - tt.x, w1 = ch.y - tt.y, w2 = ch.z - tt.z, w3 = ch.w - tt.w;
                float al = qsum(w0*nn4.x + w1*nn4.y + w2*nn4.z + w3*nn4.w);  // (h-t).n
                float be = qsum(w0*qv.x + w1*qv.y + w2*qv.z + w3*qv.w);      // (h-t).q
                float u0 = w0 + rr4.x - al*nn4.x, u1 = w1 + rr4.y - al*nn4.y,
                      u2 = w2 + rr4.z - al*nn4.z, u3 = w3 + rr4.w - al*nn4.w;
                float v0 = w0 + tr4.x - be*qv.x, v1 = w1 + tr4.y - be*qv.y,
                      v2 = w2 + tr4.z - be*qv.z, v3 = w3 + tr4.w - be*qv.w;
                float ssq = qsum(u0*u0 + u1*u1 + u2*u2 + u3*u3 +
                                 v0*v0 + v1*v1 + v2*v2 + v3*v3);
                float es = __expf(__expf(-ssq));   // exp(score*score_t), arg in (0,1]
                a0 += es * ch.x; a1 += es * ch.y; a2 += es * ch.z; a3 += es * ch.w;
                se += es;
            }
        } else {
            // ---- category graph (TransE) ----
            float4 tt = ld4(cemb, (d - N) * 16 + l, f);
            float4 r6 = *reinterpret_cast<float4*>(&srel[6 * D + l * 4]);
            float b0 = r6.x - tt.x, b1 = r6.y - tt.y, b2 = r6.z - tt.z, b3 = r6.w - tt.w;
            int i = i0 + q;
            unsigned pkA = 0; float4 hA = make_float4(0, 0, 0, 0);
            if (i < i1) { pkA = recs[i]; hA = ld4(cemb, (int)pkA * 16 + l, f); }
            for (; i < i1; i += 4) {
                float4 ch = hA;
                if (i + 4 < i1) { pkA = recs[i + 4]; hA = ld4(cemb, (int)pkA * 16 + l, f); }
                float d0 = ch.x + b0, d1 = ch.y + b1, d2 = ch.z + b2, d3 = ch.w + b3;
                float ssq = qsum(d0*d0 + d1*d1 + d2*d2 + d3*d3);
                float es = __expf(__expf(-ssq));
                a0 += es * ch.x; a1 += es * ch.y; a2 += es * ch.z; a3 += es * ch.w;
                se += es;
            }
        }
        // ---- cross-quarter combine (sum the 4 edge slots) ----
        a0 += __shfl_xor(a0, 16, 64); a0 += __shfl_xor(a0, 32, 64);
        a1 += __shfl_xor(a1, 16, 64); a1 += __shfl_xor(a1, 32, 64);
        a2 += __shfl_xor(a2, 16, 64); a2 += __shfl_xor(a2, 32, 64);
        a3 += __shfl_xor(a3, 16, 64); a3 += __shfl_xor(a3, 32, 64);
        se += __shfl_xor(se, 16, 64); se += __shfl_xor(se, 32, 64);
        float inv = (se > 0.f) ? 1.f / se : 0.f;   // zero-degree row -> zeros
        if (q == 0) {
            int oi = d * 16 + l;
            if (f) {
                reinterpret_cast<float4*>(out)[oi] = make_float4(a0*inv, a1*inv, a2*inv, a3*inv);
            } else {
                ushort4 o;
                o.x = f2bf(a0*inv); o.y = f2bf(a1*inv); o.z = f2bf(a2*inv); o.w = f2bf(a3*inv);
                reinterpret_cast<ushort4*>(out)[oi] = o;
            }
        }
    }
}

extern "C" void kernel_launch(void* const* d_in, const int* in_sizes, int n_in,
                              void* d_out, int out_size, void* d_ws, size_t ws_size,
                              hipStream_t stream) {
    const void* nfeat    = d_in[0];
    const void* cemb     = d_in[1];
    const void* rel_emb  = d_in[2];
    const void* norm_emb = d_in[3];
    const void* hour_emb = d_in[4];
    const void* trw      = d_in[5];
    const void* trb      = d_in[6];
    const int* src    = (const int*)d_in[7];
    const int* dst    = (const int*)d_in[8];
    const int* ftype  = (const int*)d_in[9];
    const int* hourid = (const int*)d_in[10];
    const int* csrc   = (const int*)d_in[11];
    const int* cdst   = (const int*)d_in[12];

    const int N  = in_sizes[0] / D;
    const int NC = in_sizes[1] / D;
    const int E  = in_sizes[7];
    const int EC = in_sizes[11];
    const int M  = N + NC;          // unified dst space
    const int ET = E + EC;          // unified edge count

    // ---- ws layout (4B units): parts(256) cnt(M) | row(M) trel(384) recs(ET) ----
    int* ws     = (int*)d_ws;
    int* parts  = ws;
    int* cnt    = ws + 256;
    int* row    = cnt + M;
    float* trel = (float*)(row + M);
    unsigned* recs = (unsigned*)(trel + HOUR_PERIOD * D);

    // zero parts + cnt (contiguous, capture-safe)
    hipMemsetAsync(ws, 0, (size_t)(256 + M) * 4, stream);

    int nparts = (M + 1023) / 1024;                 // 99 for M=100500 (<= 256)
    int histT  = (E + 3) / 4 + (EC + 3) / 4;

    k_hist<<<(histT + 255) / 256, 256, 0, stream>>>(dst, cdst, cnt,
                                                    hour_emb, trw, trb, rel_emb,
                                                    trel, E, EC, N);
    k_scan<<<nparts, 256, 0, stream>>>(cnt, parts, row, M);
    k_scatter<<<(histT + 255) / 256, 256, 0, stream>>>(src, dst, ftype, hourid,
                                                       csrc, cdst, row, recs, E, EC, N);
    k_fused<<<(M + 15) / 16, 256, 0, stream>>>(nfeat, cemb, rel_emb, norm_emb,
                                               trel, row, cnt, recs,
                                               d_out, N, M);
}

// Round 10
// 224.520 us; speedup vs baseline: 4.8303x; 1.1460x over previous
//
#include <hip/hip_runtime.h>

#define D 64
#define HOUR_PERIOD 6

// ---------- dtype helpers ----------
__device__ __forceinline__ float bf2f(unsigned short u) {
    union { unsigned int i; float f; } v; v.i = ((unsigned int)u) << 16; return v.f;
}
__device__ __forceinline__ unsigned short f2bf(float f) {
    union { float fl; unsigned int i; } v; v.fl = f;
    unsigned int x = v.i;
    return (unsigned short)((x + 0x7fffu + ((x >> 16) & 1u)) >> 16);
}
__device__ __forceinline__ float4 ld4(const void* base, int idx4, int fp32) {
    if (fp32) return reinterpret_cast<const float4*>(base)[idx4];
    ushort4 u = reinterpret_cast<const ushort4*>(base)[idx4];
    return make_float4(bf2f(u.x), bf2f(u.y), bf2f(u.z), bf2f(u.w));
}
__device__ __forceinline__ float ld1(const void* base, int i, int fp32) {
    return fp32 ? reinterpret_cast<const float*>(base)[i]
                : bf2f(reinterpret_cast<const unsigned short*>(base)[i]);
}
// per-wave dtype detect: rel_emb rows are L2-normalized -> |v|<=1 if truly bf16
__device__ __forceinline__ int detect_f(const void* rel_emb) {
    int lane = threadIdx.x & 63;
    float da = bf2f(reinterpret_cast<const unsigned short*>(rel_emb)[lane]);
    float db = bf2f(reinterpret_cast<const unsigned short*>(rel_emb)[lane + 64]);
    int bad = (!(fabsf(da) <= 100.f)) || (!(fabsf(db) <= 100.f));
    unsigned long long m = __ballot(bad);
    return (m != 0ull) ? 1 : 0;   // 1 => fp32 inputs/outputs
}

// ---------- DPP 16-lane row reduction (VALU pipe, no DS traffic) ----------
template <int CTRL>
__device__ __forceinline__ float dpp_add(float v) {
    union { float f; int i; } a, b;
    a.f = v;
    b.i = __builtin_amdgcn_update_dpp(0, a.i, CTRL, 0xF, 0xF, true);
    return v + b.f;
}
__device__ __forceinline__ float qsum(float v) {
    v = dpp_add<0x128>(v);   // row_ror:8
    v = dpp_add<0x124>(v);   // row_ror:4
    v = dpp_add<0x122>(v);   // row_ror:2
    v = dpp_add<0x121>(v);   // row_ror:1
    return v;
}
__device__ __forceinline__ float wsum64(float v) {
    #pragma unroll
    for (int off = 32; off; off >>= 1) v += __shfl_xor(v, off, 64);
    return v;
}
__device__ __forceinline__ int wredi(int v) {
    #pragma unroll
    for (int off = 32; off; off >>= 1) v += __shfl_xor(v, off, 64);
    return v;
}

// ---------- hist (+ trel in blocks 0..5): count AND record per-edge rank ----------
// rank[e] = this edge's arrival order within its dst segment (atomicAdd return).
__global__ void k_hist(const int* __restrict__ dst, const int* __restrict__ cdst,
                       int* __restrict__ cnt, int* __restrict__ rank,
                       const void* __restrict__ hour_emb, const void* __restrict__ trw,
                       const void* __restrict__ trb, const void* __restrict__ rel_emb,
                       float* __restrict__ trel, int E, int EC, int N) {
    int b = blockIdx.x, t = threadIdx.x;
    if (b < HOUR_PERIOD) {
        __shared__ float mix[D];
        int f = 0;
        if (t < 64) {
            f = detect_f(rel_emb);
            int last = (b - 1 + HOUR_PERIOD) % HOUR_PERIOD;
            int next = (b + 1) % HOUR_PERIOD;
            mix[t] = (ld1(hour_emb, last * D + t, f) + ld1(hour_emb, b * D + t, f) +
                      ld1(hour_emb, next * D + t, f)) * (1.f / 3.f);
        }
        __syncthreads();
        if (t < 64) {
            float y = ld1(trb, t, f);
            #pragma unroll
            for (int k = 0; k < D; ++k) y += mix[k] * ld1(trw, t * D + k, f);
            float ss = wsum64(y * y);
            trel[b * D + t] = y / fmaxf(sqrtf(ss), 1e-12f);
        }
    }
    int tid = b * 256 + t;
    int mainT = (E + 3) >> 2;
    if (tid < mainT) {
        int e4 = tid * 4;
        if (e4 + 3 < E) {
            int4 dv = reinterpret_cast<const int4*>(dst)[tid];
            int4 rv;
            rv.x = atomicAdd(&cnt[dv.x], 1);
            rv.y = atomicAdd(&cnt[dv.y], 1);
            rv.z = atomicAdd(&cnt[dv.z], 1);
            rv.w = atomicAdd(&cnt[dv.w], 1);
            reinterpret_cast<int4*>(rank)[tid] = rv;
        } else {
            for (int k = e4; k < E; ++k) rank[k] = atomicAdd(&cnt[dst[k]], 1);
        }
    } else {
        int j = tid - mainT, e4 = j * 4;
        if (e4 + 3 < EC && (E & 3) == 0) {
            int4 dv = reinterpret_cast<const int4*>(cdst)[j];
            int4 rv;
            rv.x = atomicAdd(&cnt[N + dv.x], 1);
            rv.y = atomicAdd(&cnt[N + dv.y], 1);
            rv.z = atomicAdd(&cnt[N + dv.z], 1);
            rv.w = atomicAdd(&cnt[N + dv.w], 1);
            reinterpret_cast<int4*>(rank + E)[j] = rv;
        } else {
            for (int k = e4; k < EC; ++k) rank[E + k] = atomicAdd(&cnt[N + cdst[k]], 1);
        }
    }
}

// ---------- single-dispatch scan with decoupled lookback (row stays static) ------
// Each block publishes parts[b]=total+1 (release) BEFORE any spin -> deadlock-free.
__global__ void k_scan(const int* __restrict__ cnt, int* __restrict__ parts,
                       int* __restrict__ row, int n) {
    __shared__ int smw[4], smb[4];
    int b = blockIdx.x, t = threadIdx.x;
    int lane = t & 63, wv = t >> 6;
    int idx = b * 256 + t, i0 = idx * 4;
    int c0 = 0, c1 = 0, c2 = 0, c3 = 0;
    if (i0 + 3 < n) {
        int4 c = reinterpret_cast<const int4*>(cnt)[idx];
        c0 = c.x; c1 = c.y; c2 = c.z; c3 = c.w;
    } else {
        if (i0 + 0 < n) c0 = cnt[i0 + 0];
        if (i0 + 1 < n) c1 = cnt[i0 + 1];
        if (i0 + 2 < n) c2 = cnt[i0 + 2];
        if (i0 + 3 < n) c3 = cnt[i0 + 3];
    }
    int s = c0 + c1 + c2 + c3;
    int x = s;   // inclusive wave scan
    #pragma unroll
    for (int off = 1; off < 64; off <<= 1) {
        int y = __shfl_up(x, off, 64);
        if (lane >= off) x += y;
    }
    if (lane == 63) smw[wv] = x;
    __syncthreads();
    if (t == 0) {
        int total = smw[0] + smw[1] + smw[2] + smw[3];
        __hip_atomic_store(&parts[b], total + 1, __ATOMIC_RELEASE, __HIP_MEMORY_SCOPE_AGENT);
    }
    // lookback: thread t spins on parts[t] for t < b  (nparts <= 256 guaranteed)
    int pv = 0;
    if (t < b) {
        int v;
        while ((v = __hip_atomic_load(&parts[t], __ATOMIC_ACQUIRE,
                                      __HIP_MEMORY_SCOPE_AGENT)) == 0)
            __builtin_amdgcn_s_sleep(2);
        pv = v - 1;
    }
    pv = wredi(pv);
    if (lane == 0) smb[wv] = pv;
    __syncthreads();
    int base = smb[0] + smb[1] + smb[2] + smb[3];
    int wbase = 0;
    #pragma unroll
    for (int w = 0; w < 4; ++w) wbase += (w < wv) ? smw[w] : 0;
    int run = base + wbase + (x - s);   // exclusive prefix
    if (i0 + 0 < n) { row[i0 + 0] = run; run += c0; }
    if (i0 + 1 < n) { row[i0 + 1] = run; run += c1; }
    if (i0 + 2 < n) { row[i0 + 2] = run; run += c2; }
    if (i0 + 3 < n) { row[i0 + 3] = run; run += c3; }
}

// ---------- placement: NO atomics. pos = row[d] + rank[e]; recs[pos] = packed ----
// main: src(17b) | ftype(3b)<<17 | hour(3b)<<20 ; cat: csrc plain
__global__ void k_place(const int* __restrict__ src, const int* __restrict__ dst,
                        const int* __restrict__ ft, const int* __restrict__ hh,
                        const int* __restrict__ csrc, const int* __restrict__ cdst,
                        const int* __restrict__ row, const int* __restrict__ rank,
                        unsigned* __restrict__ recs, int E, int EC, int N) {
    int tid = blockIdx.x * blockDim.x + threadIdx.x;
    int mainT = (E + 3) / 4;
    if (tid < mainT) {
        int i = tid * 4;
        if (i + 3 < E) {
            int4 s4 = reinterpret_cast<const int4*>(src)[tid];
            int4 d4 = reinterpret_cast<const int4*>(dst)[tid];
            int4 f4 = reinterpret_cast<const int4*>(ft)[tid];
            int4 h4 = reinterpret_cast<const int4*>(hh)[tid];
            int4 r4 = reinterpret_cast<const int4*>(rank)[tid];
            recs[row[d4.x] + r4.x] = (unsigned)s4.x | ((unsigned)f4.x << 17) | ((unsigned)h4.x << 20);
            recs[row[d4.y] + r4.y] = (unsigned)s4.y | ((unsigned)f4.y << 17) | ((unsigned)h4.y << 20);
            recs[row[d4.z] + r4.z] = (unsigned)s4.z | ((unsigned)f4.z << 17) | ((unsigned)h4.z << 20);
            recs[row[d4.w] + r4.w] = (unsigned)s4.w | ((unsigned)f4.w << 17) | ((unsigned)h4.w << 20);
        } else {
            for (int k = i; k < E; ++k)
                recs[row[dst[k]] + rank[k]] =
                    (unsigned)src[k] | ((unsigned)ft[k] << 17) | ((unsigned)hh[k] << 20);
        }
    } else {
        int j = (tid - mainT) * 4;
        if (j + 3 < EC && (E & 3) == 0) {
            int4 s4 = reinterpret_cast<const int4*>(csrc)[tid - mainT];
            int4 d4 = reinterpret_cast<const int4*>(cdst)[tid - mainT];
            int4 r4 = reinterpret_cast<const int4*>(rank + E)[tid - mainT];
            recs[row[N + d4.x] + r4.x] = (unsigned)s4.x;
            recs[row[N + d4.y] + r4.y] = (unsigned)s4.y;
            recs[row[N + d4.z] + r4.z] = (unsigned)s4.z;
            recs[row[N + d4.w] + r4.w] = (unsigned)s4.w;
        } else {
            for (int k = j; k < EC; ++k)
                recs[row[N + cdst[k]] + rank[E + k]] = (unsigned)csrc[k];
        }
    }
}

// ---------- fused aggregation: one wave per node, 4 edges across quarter-waves ----
// i0 = row[d] (static), i1 = i0 + cnt[d].
// out[d] = sum_e es_e * h_e / sum_e es_e  (softmax denominator factors out).
__launch_bounds__(256, 4)
__global__ void k_fused(const void* __restrict__ nfeat, const void* __restrict__ cemb,
                        const void* __restrict__ rel_emb, const void* __restrict__ norm_emb,
                        const float* __restrict__ trel,
                        const int* __restrict__ row, const int* __restrict__ cnt,
                        const unsigned* __restrict__ recs,
                        void* __restrict__ out, int N, int M) {
    int t = threadIdx.x;
    int f = detect_f(rel_emb);
    __shared__ float srel[7 * D], snorm[7 * D], strel[HOUR_PERIOD * D];
    for (int i = t; i < 7 * D; i += 256) srel[i] = ld1(rel_emb, i, f);
    for (int i = t; i < 7 * D; i += 256) snorm[i] = ld1(norm_emb, i, f);
    for (int i = t; i < HOUR_PERIOD * D; i += 256) strel[i] = trel[i];
    __syncthreads();
    int lane = t & 63, w = t >> 6;
    int l = lane & 15, q = lane >> 4;     // dim quarter / edge slot
    int dbase = (blockIdx.x * 4 + w) * 4; // 4 consecutive nodes per wave
    for (int d = dbase; d < dbase + 4 && d < M; ++d) {
        int i0 = row[d];
        int i1 = i0 + cnt[d];
        float a0 = 0.f, a1 = 0.f, a2 = 0.f, a3 = 0.f, se = 0.f;
        if (d < N) {
            // ---- main graph (TransH on relation + time hyperplanes) ----
            float4 tt = ld4(nfeat, d * 16 + l, f);
            float4 qv = *reinterpret_cast<float4*>(&snorm[5 * D + l * 4]);
            int i = i0 + q;
            unsigned pkA = 0; float4 hA = make_float4(0, 0, 0, 0);
            if (i < i1) { pkA = recs[i]; hA = ld4(nfeat, (int)(pkA & 0x1FFFF) * 16 + l, f); }
            for (; i < i1; i += 4) {
                unsigned cpk = pkA; float4 ch = hA;
                if (i + 4 < i1) { pkA = recs[i + 4]; hA = ld4(nfeat, (int)(pkA & 0x1FFFF) * 16 + l, f); }
                int ft = (cpk >> 17) & 7, hh = (cpk >> 20) & 7;
                float4 nn4 = *reinterpret_cast<float4*>(&snorm[ft * D + l * 4]);
                float4 rr4 = *reinterpret_cast<float4*>(&srel[ft * D + l * 4]);
                float4 tr4 = *reinterpret_cast<float4*>(&strel[hh * D + l * 4]);
                float w0 = ch.x - tt.x, w1 = ch.y - tt.y, w2 = ch.z - tt.z, w3 = ch.w - tt.w;
                float al = qsum(w0*nn4.x + w1*nn4.y + w2*nn4.z + w3*nn4.w);  // (h-t).n
                float be = qsum(w0*qv.x + w1*qv.y + w2*qv.z + w3*qv.w);      // (h-t).q
                float u0 = w0 + rr4.x - al*nn4.x, u1 = w1 + rr4.y - al*nn4.y,
                      u2 = w2 + rr4.z - al*nn4.z, u3 = w3 + rr4.w - al*nn4.w;
                float v0 = w0 + tr4.x - be*qv.x, v1 = w1 + tr4.y - be*qv.y,
                      v2 = w2 + tr4.z - be*qv.z, v3 = w3 + tr4.w - be*qv.w;
                float ssq = qsum(u0*u0 + u1*u1 + u2*u2 + u3*u3 +
                                 v0*v0 + v1*v1 + v2*v2 + v3*v3);
                float es = __expf(__expf(-ssq));   // exp(score*score_t), arg in (0,1]
                a0 += es * ch.x; a1 += es * ch.y; a2 += es * ch.z; a3 += es * ch.w;
                se += es;
            }
        } else {
            // ---- category graph (TransE) ----
            float4 tt = ld4(cemb, (d - N) * 16 + l, f);
            float4 r6 = *reinterpret_cast<float4*>(&srel[6 * D + l * 4]);
            float b0 = r6.x - tt.x, b1 = r6.y - tt.y, b2 = r6.z - tt.z, b3 = r6.w - tt.w;
            int i = i0 + q;
            unsigned pkA = 0; float4 hA = make_float4(0, 0, 0, 0);
            if (i < i1) { pkA = recs[i]; hA = ld4(cemb, (int)pkA * 16 + l, f); }
            for (; i < i1; i += 4) {
                float4 ch = hA;
                if (i + 4 < i1) { pkA = recs[i + 4]; hA = ld4(cemb, (int)pkA * 16 + l, f); }
                float d0 = ch.x + b0, d1 = ch.y + b1, d2 = ch.z + b2, d3 = ch.w + b3;
                float ssq = qsum(d0*d0 + d1*d1 + d2*d2 + d3*d3);
                float es = __expf(__expf(-ssq));
                a0 += es * ch.x; a1 += es * ch.y; a2 += es * ch.z; a3 += es * ch.w;
                se += es;
            }
        }
        // ---- cross-quarter combine (sum the 4 edge slots) ----
        a0 += __shfl_xor(a0, 16, 64); a0 += __shfl_xor(a0, 32, 64);
        a1 += __shfl_xor(a1, 16, 64); a1 += __shfl_xor(a1, 32, 64);
        a2 += __shfl_xor(a2, 16, 64); a2 += __shfl_xor(a2, 32, 64);
        a3 += __shfl_xor(a3, 16, 64); a3 += __shfl_xor(a3, 32, 64);
        se += __shfl_xor(se, 16, 64); se += __shfl_xor(se, 32, 64);
        float inv = (se > 0.f) ? 1.f / se : 0.f;   // zero-degree row -> zeros
        if (q == 0) {
            int oi = d * 16 + l;
            if (f) {
                reinterpret_cast<float4*>(out)[oi] = make_float4(a0*inv, a1*inv, a2*inv, a3*inv);
            } else {
                ushort4 o;
                o.x = f2bf(a0*inv); o.y = f2bf(a1*inv); o.z = f2bf(a2*inv); o.w = f2bf(a3*inv);
                reinterpret_cast<ushort4*>(out)[oi] = o;
            }
        }
    }
}

extern "C" void kernel_launch(void* const* d_in, const int* in_sizes, int n_in,
                              void* d_out, int out_size, void* d_ws, size_t ws_size,
                              hipStream_t stream) {
    const void* nfeat    = d_in[0];
    const void* cemb     = d_in[1];
    const void* rel_emb  = d_in[2];
    const void* norm_emb = d_in[3];
    const void* hour_emb = d_in[4];
    const void* trw      = d_in[5];
    const void* trb      = d_in[6];
    const int* src    = (const int*)d_in[7];
    const int* dst    = (const int*)d_in[8];
    const int* ftype  = (const int*)d_in[9];
    const int* hourid = (const int*)d_in[10];
    const int* csrc   = (const int*)d_in[11];
    const int* cdst   = (const int*)d_in[12];

    const int N  = in_sizes[0] / D;
    const int NC = in_sizes[1] / D;
    const int E  = in_sizes[7];
    const int EC = in_sizes[11];
    const int M  = N + NC;          // unified dst space
    const int ET = E + EC;          // unified edge count

    // ---- ws layout (4B units): parts(256) cnt(M) | row(M) trel(384) rank(ET) recs(ET)
    // total ~ 7.9 MB; ws_size >= ~30 MB (verified empirically in round 2: K=1 chunking)
    int* ws     = (int*)d_ws;
    int* parts  = ws;
    int* cnt    = ws + 256;
    int* row    = cnt + M;
    float* trel = (float*)(row + M);
    int* rank   = (int*)(trel + HOUR_PERIOD * D);
    unsigned* recs = (unsigned*)(rank + ET);

    // zero parts + cnt (contiguous, capture-safe)
    hipMemsetAsync(ws, 0, (size_t)(256 + M) * 4, stream);

    int nparts = (M + 1023) / 1024;                 // 99 for M=100500 (<= 256)
    int histT  = (E + 3) / 4 + (EC + 3) / 4;

    k_hist<<<(histT + 255) / 256, 256, 0, stream>>>(dst, cdst, cnt, rank,
                                                    hour_emb, trw, trb, rel_emb,
                                                    trel, E, EC, N);
    k_scan<<<nparts, 256, 0, stream>>>(cnt, parts, row, M);
    k_place<<<(histT + 255) / 256, 256, 0, stream>>>(src, dst, ftype, hourid,
                                                     csrc, cdst, row, rank, recs,
                                                     E, EC, N);
    k_fused<<<(M + 15) / 16, 256, 0, stream>>>(nfeat, cemb, rel_emb, norm_emb,
                                               trel, row, cnt, recs,
                                               d_out, N, M);
}

// Round 11
// 222.591 us; speedup vs baseline: 4.8722x; 1.0087x over previous
//
#include <hip/hip_runtime.h>

#define D 64
#define HOUR_PERIOD 6

// ---------- dtype helpers ----------
__device__ __forceinline__ float bf2f(unsigned short u) {
    union { unsigned int i; float f; } v; v.i = ((unsigned int)u) << 16; return v.f;
}
__device__ __forceinline__ unsigned short f2bf(float f) {
    union { float fl; unsigned int i; } v; v.fl = f;
    unsigned int x = v.i;
    return (unsigned short)((x + 0x7fffu + ((x >> 16) & 1u)) >> 16);
}
__device__ __forceinline__ float4 ld4(const void* base, int idx4, int fp32) {
    if (fp32) return reinterpret_cast<const float4*>(base)[idx4];
    ushort4 u = reinterpret_cast<const ushort4*>(base)[idx4];
    return make_float4(bf2f(u.x), bf2f(u.y), bf2f(u.z), bf2f(u.w));
}
__device__ __forceinline__ float ld1(const void* base, int i, int fp32) {
    return fp32 ? reinterpret_cast<const float*>(base)[i]
                : bf2f(reinterpret_cast<const unsigned short*>(base)[i]);
}
// per-wave dtype detect: rel_emb rows are L2-normalized -> |v|<=1 if truly bf16
__device__ __forceinline__ int detect_f(const void* rel_emb) {
    int lane = threadIdx.x & 63;
    float da = bf2f(reinterpret_cast<const unsigned short*>(rel_emb)[lane]);
    float db = bf2f(reinterpret_cast<const unsigned short*>(rel_emb)[lane + 64]);
    int bad = (!(fabsf(da) <= 100.f)) || (!(fabsf(db) <= 100.f));
    unsigned long long m = __ballot(bad);
    return (m != 0ull) ? 1 : 0;   // 1 => fp32 inputs/outputs
}

// ---------- DPP 16-lane row reduction (VALU pipe, no DS traffic) ----------
template <int CTRL>
__device__ __forceinline__ float dpp_add(float v) {
    union { float f; int i; } a, b;
    a.f = v;
    b.i = __builtin_amdgcn_update_dpp(0, a.i, CTRL, 0xF, 0xF, true);
    return v + b.f;
}
__device__ __forceinline__ float qsum(float v) {
    v = dpp_add<0x128>(v);   // row_ror:8
    v = dpp_add<0x124>(v);   // row_ror:4
    v = dpp_add<0x122>(v);   // row_ror:2
    v = dpp_add<0x121>(v);   // row_ror:1
    return v;
}
__device__ __forceinline__ float wsum64(float v) {
    #pragma unroll
    for (int off = 32; off; off >>= 1) v += __shfl_xor(v, off, 64);
    return v;
}
__device__ __forceinline__ int wredi(int v) {
    #pragma unroll
    for (int off = 32; off; off >>= 1) v += __shfl_xor(v, off, 64);
    return v;
}

// ---------- hist (+ trel in blocks 0..5): count AND record per-edge rank ----------
// rank[e] = this edge's arrival order within its dst segment (atomicAdd return).
__global__ void k_hist(const int* __restrict__ dst, const int* __restrict__ cdst,
                       int* __restrict__ cnt, int* __restrict__ rank,
                       const void* __restrict__ hour_emb, const void* __restrict__ trw,
                       const void* __restrict__ trb, const void* __restrict__ rel_emb,
                       float* __restrict__ trel, int E, int EC, int N) {
    int b = blockIdx.x, t = threadIdx.x;
    if (b < HOUR_PERIOD) {
        __shared__ float mix[D];
        int f = 0;
        if (t < 64) {
            f = detect_f(rel_emb);
            int last = (b - 1 + HOUR_PERIOD) % HOUR_PERIOD;
            int next = (b + 1) % HOUR_PERIOD;
            mix[t] = (ld1(hour_emb, last * D + t, f) + ld1(hour_emb, b * D + t, f) +
                      ld1(hour_emb, next * D + t, f)) * (1.f / 3.f);
        }
        __syncthreads();
        if (t < 64) {
            float y = ld1(trb, t, f);
            #pragma unroll
            for (int k = 0; k < D; ++k) y += mix[k] * ld1(trw, t * D + k, f);
            float ss = wsum64(y * y);
            trel[b * D + t] = y / fmaxf(sqrtf(ss), 1e-12f);
        }
    }
    int tid = b * 256 + t;
    int mainT = (E + 3) >> 2;
    if (tid < mainT) {
        int e4 = tid * 4;
        if (e4 + 3 < E) {
            int4 dv = reinterpret_cast<const int4*>(dst)[tid];
            int4 rv;
            rv.x = atomicAdd(&cnt[dv.x], 1);
            rv.y = atomicAdd(&cnt[dv.y], 1);
            rv.z = atomicAdd(&cnt[dv.z], 1);
            rv.w = atomicAdd(&cnt[dv.w], 1);
            reinterpret_cast<int4*>(rank)[tid] = rv;
        } else {
            for (int k = e4; k < E; ++k) rank[k] = atomicAdd(&cnt[dst[k]], 1);
        }
    } else {
        int j = tid - mainT, e4 = j * 4;
        if (e4 + 3 < EC && (E & 3) == 0) {
            int4 dv = reinterpret_cast<const int4*>(cdst)[j];
            int4 rv;
            rv.x = atomicAdd(&cnt[N + dv.x], 1);
            rv.y = atomicAdd(&cnt[N + dv.y], 1);
            rv.z = atomicAdd(&cnt[N + dv.z], 1);
            rv.w = atomicAdd(&cnt[N + dv.w], 1);
            reinterpret_cast<int4*>(rank + E)[j] = rv;
        } else {
            for (int k = e4; k < EC; ++k) rank[E + k] = atomicAdd(&cnt[N + cdst[k]], 1);
        }
    }
}

// ---------- single-dispatch scan with decoupled lookback (row stays static) ------
// Each block publishes parts[b]=total+1 (release) BEFORE any spin -> deadlock-free.
__global__ void k_scan(const int* __restrict__ cnt, int* __restrict__ parts,
                       int* __restrict__ row, int n) {
    __shared__ int smw[4], smb[4];
    int b = blockIdx.x, t = threadIdx.x;
    int lane = t & 63, wv = t >> 6;
    int idx = b * 256 + t, i0 = idx * 4;
    int c0 = 0, c1 = 0, c2 = 0, c3 = 0;
    if (i0 + 3 < n) {
        int4 c = reinterpret_cast<const int4*>(cnt)[idx];
        c0 = c.x; c1 = c.y; c2 = c.z; c3 = c.w;
    } else {
        if (i0 + 0 < n) c0 = cnt[i0 + 0];
        if (i0 + 1 < n) c1 = cnt[i0 + 1];
        if (i0 + 2 < n) c2 = cnt[i0 + 2];
        if (i0 + 3 < n) c3 = cnt[i0 + 3];
    }
    int s = c0 + c1 + c2 + c3;
    int x = s;   // inclusive wave scan
    #pragma unroll
    for (int off = 1; off < 64; off <<= 1) {
        int y = __shfl_up(x, off, 64);
        if (lane >= off) x += y;
    }
    if (lane == 63) smw[wv] = x;
    __syncthreads();
    if (t == 0) {
        int total = smw[0] + smw[1] + smw[2] + smw[3];
        __hip_atomic_store(&parts[b], total + 1, __ATOMIC_RELEASE, __HIP_MEMORY_SCOPE_AGENT);
    }
    // lookback: thread t spins on parts[t] for t < b  (nparts <= 256 guaranteed)
    int pv = 0;
    if (t < b) {
        int v;
        while ((v = __hip_atomic_load(&parts[t], __ATOMIC_ACQUIRE,
                                      __HIP_MEMORY_SCOPE_AGENT)) == 0)
            __builtin_amdgcn_s_sleep(2);
        pv = v - 1;
    }
    pv = wredi(pv);
    if (lane == 0) smb[wv] = pv;
    __syncthreads();
    int base = smb[0] + smb[1] + smb[2] + smb[3];
    int wbase = 0;
    #pragma unroll
    for (int w = 0; w < 4; ++w) wbase += (w < wv) ? smw[w] : 0;
    int run = base + wbase + (x - s);   // exclusive prefix
    if (i0 + 0 < n) { row[i0 + 0] = run; run += c0; }
    if (i0 + 1 < n) { row[i0 + 1] = run; run += c1; }
    if (i0 + 2 < n) { row[i0 + 2] = run; run += c2; }
    if (i0 + 3 < n) { row[i0 + 3] = run; run += c3; }
}

// ---------- placement: NO atomics. pos = row[d] + rank[e]; recs[pos] = packed ----
// main: src(17b) | ftype(3b)<<17 | hour(3b)<<20 ; cat: csrc plain
__global__ void k_place(const int* __restrict__ src, const int* __restrict__ dst,
                        const int* __restrict__ ft, const int* __restrict__ hh,
                        const int* __restrict__ csrc, const int* __restrict__ cdst,
                        const int* __restrict__ row, const int* __restrict__ rank,
                        unsigned* __restrict__ recs, int E, int EC, int N) {
    int tid = blockIdx.x * blockDim.x + threadIdx.x;
    int mainT = (E + 3) / 4;
    if (tid < mainT) {
        int i = tid * 4;
        if (i + 3 < E) {
            int4 s4 = reinterpret_cast<const int4*>(src)[tid];
            int4 d4 = reinterpret_cast<const int4*>(dst)[tid];
            int4 f4 = reinterpret_cast<const int4*>(ft)[tid];
            int4 h4 = reinterpret_cast<const int4*>(hh)[tid];
            int4 r4 = reinterpret_cast<const int4*>(rank)[tid];
            recs[row[d4.x] + r4.x] = (unsigned)s4.x | ((unsigned)f4.x << 17) | ((unsigned)h4.x << 20);
            recs[row[d4.y] + r4.y] = (unsigned)s4.y | ((unsigned)f4.y << 17) | ((unsigned)h4.y << 20);
            recs[row[d4.z] + r4.z] = (unsigned)s4.z | ((unsigned)f4.z << 17) | ((unsigned)h4.z << 20);
            recs[row[d4.w] + r4.w] = (unsigned)s4.w | ((unsigned)f4.w << 17) | ((unsigned)h4.w << 20);
        } else {
            for (int k = i; k < E; ++k)
                recs[row[dst[k]] + rank[k]] =
                    (unsigned)src[k] | ((unsigned)ft[k] << 17) | ((unsigned)hh[k] << 20);
        }
    } else {
        int j = (tid - mainT) * 4;
        if (j + 3 < EC && (E & 3) == 0) {
            int4 s4 = reinterpret_cast<const int4*>(csrc)[tid - mainT];
            int4 d4 = reinterpret_cast<const int4*>(cdst)[tid - mainT];
            int4 r4 = reinterpret_cast<const int4*>(rank + E)[tid - mainT];
            recs[row[N + d4.x] + r4.x] = (unsigned)s4.x;
            recs[row[N + d4.y] + r4.y] = (unsigned)s4.y;
            recs[row[N + d4.z] + r4.z] = (unsigned)s4.z;
            recs[row[N + d4.w] + r4.w] = (unsigned)s4.w;
        } else {
            for (int k = j; k < EC; ++k)
                recs[row[N + cdst[k]] + rank[E + k]] = (unsigned)csrc[k];
        }
    }
}

// ---------- fused aggregation: one wave per node, 4 edges across quarter-waves ----
// i0 = row[d] (static), i1 = i0 + cnt[d].
// out[d] = sum_e es_e * h_e / sum_e es_e  (softmax denominator factors out).
// launch_bounds(256, 8): VGPR=32 allows 8 waves/SIMD -> 32 waves/CU (was 4 -> 50%).
// The extra resident waves hide the ~43% gather-latency stall seen at (256,4).
__launch_bounds__(256, 8)
__global__ void k_fused(const void* __restrict__ nfeat, const void* __restrict__ cemb,
                        const void* __restrict__ rel_emb, const void* __restrict__ norm_emb,
                        const float* __restrict__ trel,
                        const int* __restrict__ row, const int* __restrict__ cnt,
                        const unsigned* __restrict__ recs,
                        void* __restrict__ out, int N, int M) {
    int t = threadIdx.x;
    int f = detect_f(rel_emb);
    __shared__ float srel[7 * D], snorm[7 * D], strel[HOUR_PERIOD * D];
    for (int i = t; i < 7 * D; i += 256) srel[i] = ld1(rel_emb, i, f);
    for (int i = t; i < 7 * D; i += 256) snorm[i] = ld1(norm_emb, i, f);
    for (int i = t; i < HOUR_PERIOD * D; i += 256) strel[i] = trel[i];
    __syncthreads();
    int lane = t & 63, w = t >> 6;
    int l = lane & 15, q = lane >> 4;     // dim quarter / edge slot
    int dbase = (blockIdx.x * 4 + w) * 4; // 4 consecutive nodes per wave
    for (int d = dbase; d < dbase + 4 && d < M; ++d) {
        int i0 = row[d];
        int i1 = i0 + cnt[d];
        float a0 = 0.f, a1 = 0.f, a2 = 0.f, a3 = 0.f, se = 0.f;
        if (d < N) {
            // ---- main graph (TransH on relation + time hyperplanes) ----
            float4 tt = ld4(nfeat, d * 16 + l, f);
            float4 qv = *reinterpret_cast<float4*>(&snorm[5 * D + l * 4]);
            int i = i0 + q;
            unsigned pkA = 0; float4 hA = make_float4(0, 0, 0, 0);
            if (i < i1) { pkA = recs[i]; hA = ld4(nfeat, (int)(pkA & 0x1FFFF) * 16 + l, f); }
            for (; i < i1; i += 4) {
                unsigned cpk = pkA; float4 ch = hA;
                if (i + 4 < i1) { pkA = recs[i + 4]; hA = ld4(nfeat, (int)(pkA & 0x1FFFF) * 16 + l, f); }
                int ft = (cpk >> 17) & 7, hh = (cpk >> 20) & 7;
                float4 nn4 = *reinterpret_cast<float4*>(&snorm[ft * D + l * 4]);
                float4 rr4 = *reinterpret_cast<float4*>(&srel[ft * D + l * 4]);
                float4 tr4 = *reinterpret_cast<float4*>(&strel[hh * D + l * 4]);
                float w0 = ch.x - tt.x, w1 = ch.y - tt.y, w2 = ch.z - tt.z, w3 = ch.w - tt.w;
                float al = qsum(w0*nn4.x + w1*nn4.y + w2*nn4.z + w3*nn4.w);  // (h-t).n
                float be = qsum(w0*qv.x + w1*qv.y + w2*qv.z + w3*qv.w);      // (h-t).q
                float u0 = w0 + rr4.x - al*nn4.x, u1 = w1 + rr4.y - al*nn4.y,
                      u2 = w2 + rr4.z - al*nn4.z, u3 = w3 + rr4.w - al*nn4.w;
                float v0 = w0 + tr4.x - be*qv.x, v1 = w1 + tr4.y - be*qv.y,
                      v2 = w2 + tr4.z - be*qv.z, v3 = w3 + tr4.w - be*qv.w;
                float ssq = qsum(u0*u0 + u1*u1 + u2*u2 + u3*u3 +
                                 v0*v0 + v1*v1 + v2*v2 + v3*v3);
                float es = __expf(__expf(-ssq));   // exp(score*score_t), arg in (0,1]
                a0 += es * ch.x; a1 += es * ch.y; a2 += es * ch.z; a3 += es * ch.w;
                se += es;
            }
        } else {
            // ---- category graph (TransE) ----
            float4 tt = ld4(cemb, (d - N) * 16 + l, f);
            float4 r6 = *reinterpret_cast<float4*>(&srel[6 * D + l * 4]);
            float b0 = r6.x - tt.x, b1 = r6.y - tt.y, b2 = r6.z - tt.z, b3 = r6.w - tt.w;
            int i = i0 + q;
            unsigned pkA = 0; float4 hA = make_float4(0, 0, 0, 0);
            if (i < i1) { pkA = recs[i]; hA = ld4(cemb, (int)pkA * 16 + l, f); }
            for (; i < i1; i += 4) {
                float4 ch = hA;
                if (i + 4 < i1) { pkA = recs[i + 4]; hA = ld4(cemb, (int)pkA * 16 + l, f); }
                float d0 = ch.x + b0, d1 = ch.y + b1, d2 = ch.z + b2, d3 = ch.w + b3;
                float ssq = qsum(d0*d0 + d1*d1 + d2*d2 + d3*d3);
                float es = __expf(__expf(-ssq));
                a0 += es * ch.x; a1 += es * ch.y; a2 += es * ch.z; a3 += es * ch.w;
                se += es;
            }
        }
        // ---- cross-quarter combine (sum the 4 edge slots) ----
        a0 += __shfl_xor(a0, 16, 64); a0 += __shfl_xor(a0, 32, 64);
        a1 += __shfl_xor(a1, 16, 64); a1 += __shfl_xor(a1, 32, 64);
        a2 += __shfl_xor(a2, 16, 64); a2 += __shfl_xor(a2, 32, 64);
        a3 += __shfl_xor(a3, 16, 64); a3 += __shfl_xor(a3, 32, 64);
        se += __shfl_xor(se, 16, 64); se += __shfl_xor(se, 32, 64);
        float inv = (se > 0.f) ? 1.f / se : 0.f;   // zero-degree row -> zeros
        if (q == 0) {
            int oi = d * 16 + l;
            if (f) {
                reinterpret_cast<float4*>(out)[oi] = make_float4(a0*inv, a1*inv, a2*inv, a3*inv);
            } else {
                ushort4 o;
                o.x = f2bf(a0*inv); o.y = f2bf(a1*inv); o.z = f2bf(a2*inv); o.w = f2bf(a3*inv);
                reinterpret_cast<ushort4*>(out)[oi] = o;
            }
        }
    }
}

extern "C" void kernel_launch(void* const* d_in, const int* in_sizes, int n_in,
                              void* d_out, int out_size, void* d_ws, size_t ws_size,
                              hipStream_t stream) {
    const void* nfeat    = d_in[0];
    const void* cemb     = d_in[1];
    const void* rel_emb  = d_in[2];
    const void* norm_emb = d_in[3];
    const void* hour_emb = d_in[4];
    const void* trw      = d_in[5];
    const void* trb      = d_in[6];
    const int* src    = (const int*)d_in[7];
    const int* dst    = (const int*)d_in[8];
    const int* ftype  = (const int*)d_in[9];
    const int* hourid = (const int*)d_in[10];
    const int* csrc   = (const int*)d_in[11];
    const int* cdst   = (const int*)d_in[12];

    const int N  = in_sizes[0] / D;
    const int NC = in_sizes[1] / D;
    const int E  = in_sizes[7];
    const int EC = in_sizes[11];
    const int M  = N + NC;          // unified dst space
    const int ET = E + EC;          // unified edge count

    // ---- ws layout (4B units): parts(256) cnt(M) | row(M) trel(384) rank(ET) recs(ET)
    // total ~ 7.9 MB; ws_size >= ~30 MB (verified empirically in round 2: K=1 chunking)
    int* ws     = (int*)d_ws;
    int* parts  = ws;
    int* cnt    = ws + 256;
    int* row    = cnt + M;
    float* trel = (float*)(row + M);
    int* rank   = (int*)(trel + HOUR_PERIOD * D);
    unsigned* recs = (unsigned*)(rank + ET);

    // zero parts + cnt (contiguous, capture-safe)
    hipMemsetAsync(ws, 0, (size_t)(256 + M) * 4, stream);

    int nparts = (M + 1023) / 1024;                 // 99 for M=100500 (<= 256)
    int histT  = (E + 3) / 4 + (EC + 3) / 4;

    k_hist<<<(histT + 255) / 256, 256, 0, stream>>>(dst, cdst, cnt, rank,
                                                    hour_emb, trw, trb, rel_emb,
                                                    trel, E, EC, N);
    k_scan<<<nparts, 256, 0, stream>>>(cnt, parts, row, M);
    k_place<<<(histT + 255) / 256, 256, 0, stream>>>(src, dst, ftype, hourid,
                                                     csrc, cdst, row, rank, recs,
                                                     E, EC, N);
    k_fused<<<(M + 15) / 16, 256, 0, stream>>>(nfeat, cemb, rel_emb, norm_emb,
                                               trel, row, cnt, recs,
                                               d_out, N, M);
}